// Round 1
// baseline (1762.343 us; speedup 1.0000x reference)
//
#include <hip/hip_runtime.h>
#include <cstdint>
#include <cstddef>

// ---------------------------------------------------------------------------
// VQ-VAE forward, fp32 baseline.
// B=16384 F=4096 H=512 D=64 M=8 K=512
// Out layout (floats): [idx 131072][z_e 8388608][z_q 8388608][emb 8388608][X 67108864]
// ws: h1 (B*256) | h2 (B*128); g2 reuses h1, g1 reuses h2.
// All fp32: argmin stability requires fp32-accurate z_e and distances.
// ---------------------------------------------------------------------------

static constexpr int BB = 16384;
static constexpr int TM = 128, TN = 128, TK = 16;

// C = act(A(MxK) @ B(KxN) + bias), act 0=leaky(0.01), 1=sigmoid
__global__ __launch_bounds__(256) void gemm_bias_act(
    const float* __restrict__ A, const float* __restrict__ Bm,
    const float* __restrict__ bias, float* __restrict__ C,
    int M, int N, int Kd, int act)
{
    __shared__ float As[TK][TM + 4];
    __shared__ float Bs[TK][TN + 4];
    const int tid = threadIdx.x;
    const int bm = blockIdx.y * TM;
    const int bn = blockIdx.x * TN;
    const int tx = tid & 15;        // 16 col-groups
    const int ty = tid >> 4;        // 16 row-groups

    // global load mapping
    const int arow = tid >> 2;            // 0..63
    const int acol = (tid & 3) << 2;      // 0,4,8,12
    const int brow = tid >> 5;            // 0..7
    const int bcol = (tid & 31) << 2;     // 0..124

    float acc[8][8];
#pragma unroll
    for (int i = 0; i < 8; i++)
#pragma unroll
        for (int j = 0; j < 8; j++) acc[i][j] = 0.f;

    const float* Ap0 = A + (size_t)(bm + arow) * Kd + acol;
    const float* Ap1 = A + (size_t)(bm + arow + 64) * Kd + acol;
    const float* Bp0 = Bm + (size_t)brow * N + bn + bcol;
    const float* Bp1 = Bm + (size_t)(brow + 8) * N + bn + bcol;

    for (int k0 = 0; k0 < Kd; k0 += TK) {
        const float4 a0 = *(const float4*)(Ap0 + k0);
        const float4 a1 = *(const float4*)(Ap1 + k0);
        const float4 b0 = *(const float4*)(Bp0 + (size_t)k0 * N);
        const float4 b1 = *(const float4*)(Bp1 + (size_t)k0 * N);
        __syncthreads();  // protect LDS from previous iteration readers
        As[acol + 0][arow] = a0.x; As[acol + 1][arow] = a0.y;
        As[acol + 2][arow] = a0.z; As[acol + 3][arow] = a0.w;
        As[acol + 0][arow + 64] = a1.x; As[acol + 1][arow + 64] = a1.y;
        As[acol + 2][arow + 64] = a1.z; As[acol + 3][arow + 64] = a1.w;
        *(float4*)&Bs[brow][bcol]     = b0;
        *(float4*)&Bs[brow + 8][bcol] = b1;
        __syncthreads();
#pragma unroll
        for (int kk = 0; kk < TK; kk++) {
            float a[8], b[8];
            *(float4*)&a[0] = *(const float4*)&As[kk][ty * 8];
            *(float4*)&a[4] = *(const float4*)&As[kk][ty * 8 + 4];
            *(float4*)&b[0] = *(const float4*)&Bs[kk][tx * 8];
            *(float4*)&b[4] = *(const float4*)&Bs[kk][tx * 8 + 4];
#pragma unroll
            for (int i = 0; i < 8; i++)
#pragma unroll
                for (int j = 0; j < 8; j++)
                    acc[i][j] = fmaf(a[i], b[j], acc[i][j]);
        }
    }

    float bv[8];
#pragma unroll
    for (int j = 0; j < 8; j++) bv[j] = bias[bn + tx * 8 + j];
#pragma unroll
    for (int i = 0; i < 8; i++) {
        const int row = bm + ty * 8 + i;
        float o[8];
#pragma unroll
        for (int j = 0; j < 8; j++) {
            float v = acc[i][j] + bv[j];
            if (act == 0) v = (v > 0.f) ? v : 0.01f * v;
            else          v = 1.0f / (1.0f + __expf(-v));
            o[j] = v;
        }
        *(float4*)&C[(size_t)row * N + bn + tx * 8]     = *(float4*)&o[0];
        *(float4*)&C[(size_t)row * N + bn + tx * 8 + 4] = *(float4*)&o[4];
    }
}

// VQ nearest-code argmin. One block = 64 positions (8 batch rows).
// Z(131072x64) vs codebook(64x512); dist = (x2 - 2*xw) + w2, argmin over k.
__global__ __launch_bounds__(512) void vq_argmin(
    const float* __restrict__ ze,   // (B,512) h-layout; Z[p][d]=ze[b*512+d*8+m]
    const float* __restrict__ cb,   // (64,512)
    float* __restrict__ idxf)       // (B*8) as float
{
    __shared__ float cbs[64 * 512];       // 128 KB, natural [d][k]
    __shared__ float As[64][68];          // [d][p_local], padded
    __shared__ float w2s[512];
    const int tid = threadIdx.x;          // 0..511
    const int p0 = blockIdx.x * 64;       // first position (p0 = b0*8)

    // stage codebook: 8192 float4
    const float4* cb4 = (const float4*)cb;
    float4* cbs4 = (float4*)cbs;
    for (int i = tid; i < 8192; i += 512) cbs4[i] = cb4[i];

    // stage Z tile: 8 contiguous h-rows = 1024 float4
    const float4* ze4 = (const float4*)(ze + (size_t)p0 * 64);
    for (int i = tid; i < 1024; i += 512) {
        float4 v = ze4[i];
        int e = i * 4;
        int bo = e >> 9, r = e & 511;
        int d = r >> 3, m = r & 7;               // m in {0,4}
        *(float4*)&As[d][bo * 8 + m] = v;        // 4 consecutive positions, same d
    }
    __syncthreads();

    // w2[k] = sum_d cb[d][k]^2 (conflict-free: consecutive k per lane)
    {
        float s = 0.f;
#pragma unroll
        for (int d = 0; d < 64; ++d) { float c = cbs[d * 512 + tid]; s = fmaf(c, c, s); }
        w2s[tid] = s;
    }
    __syncthreads();

    const int tx = tid & 63;   // 64 col-groups (k)
    const int ty = tid >> 6;   // 8 row-groups (positions)

    float acc[8][8], x2a[8];
#pragma unroll
    for (int i = 0; i < 8; i++) {
        x2a[i] = 0.f;
#pragma unroll
        for (int j = 0; j < 8; j++) acc[i][j] = 0.f;
    }

#pragma unroll 8
    for (int kk = 0; kk < 64; ++kk) {
        float a[8], b[8];
        *(float4*)&a[0] = *(const float4*)&As[kk][ty * 8];       // broadcast in wave
        *(float4*)&a[4] = *(const float4*)&As[kk][ty * 8 + 4];
        *(float4*)&b[0] = *(const float4*)&cbs[kk * 512 + tx * 8];
        *(float4*)&b[4] = *(const float4*)&cbs[kk * 512 + tx * 8 + 4];
#pragma unroll
        for (int i = 0; i < 8; i++) x2a[i] = fmaf(a[i], a[i], x2a[i]);
#pragma unroll
        for (int i = 0; i < 8; i++)
#pragma unroll
            for (int j = 0; j < 8; j++)
                acc[i][j] = fmaf(a[i], b[j], acc[i][j]);
    }

    float w2v[8];
#pragma unroll
    for (int j = 0; j < 8; j++) w2v[j] = w2s[tx * 8 + j];

#pragma unroll
    for (int i = 0; i < 8; i++) {
        float bd = 3.4e38f; int bk = 1 << 30;
#pragma unroll
        for (int j = 0; j < 8; j++) {
            float dsc = (x2a[i] - 2.0f * acc[i][j]) + w2v[j];   // ref association
            if (dsc < bd) { bd = dsc; bk = tx * 8 + j; }
        }
        // 64-lane argmin, first-index tiebreak
        for (int off = 32; off > 0; off >>= 1) {
            float od = __shfl_xor(bd, off);
            int   ok = __shfl_xor(bk, off);
            if (od < bd || (od == bd && ok < bk)) { bd = od; bk = ok; }
        }
        if (tx == i) idxf[p0 + ty * 8 + i] = (float)bk;
    }
}

// gather: zq = ze + (cb[:,idx] - ze)  (straight-through value), emb = cb[:,idx]
__global__ __launch_bounds__(256) void vq_gather(
    const float* __restrict__ ze, const float* __restrict__ idxf,
    const float* __restrict__ cb,
    float* __restrict__ zq, float* __restrict__ emb)
{
    const int t = blockIdx.x * 256 + threadIdx.x;   // 0 .. B*512/4 - 1
    const int e = t * 4;
    const int b = e >> 9, r = e & 511;
    const int d = r >> 3, m = r & 7;                // m in {0,4}
    const float4 z = *(const float4*)(ze + e);
    float q[4];
#pragma unroll
    for (int c = 0; c < 4; c++) {
        int k = (int)idxf[b * 8 + m + c];
        q[c] = cb[d * 512 + k];
    }
    float4 zq4, em4;
    zq4.x = z.x + (q[0] - z.x); zq4.y = z.y + (q[1] - z.y);
    zq4.z = z.z + (q[2] - z.z); zq4.w = z.w + (q[3] - z.w);
    em4.x = q[0]; em4.y = q[1]; em4.z = q[2]; em4.w = q[3];
    *(float4*)(zq + e) = zq4;
    *(float4*)(emb + e) = em4;
}

extern "C" void kernel_launch(void* const* d_in, const int* in_sizes, int n_in,
                              void* d_out, int out_size, void* d_ws, size_t ws_size,
                              hipStream_t stream)
{
    const float* x   = (const float*)d_in[0];
    const float* We1 = (const float*)d_in[1];
    const float* be1 = (const float*)d_in[2];
    const float* We2 = (const float*)d_in[3];
    const float* be2 = (const float*)d_in[4];
    const float* We3 = (const float*)d_in[5];
    const float* be3 = (const float*)d_in[6];
    const float* Wd1 = (const float*)d_in[7];
    const float* bd1 = (const float*)d_in[8];
    const float* Wd2 = (const float*)d_in[9];
    const float* bd2 = (const float*)d_in[10];
    const float* Wd3 = (const float*)d_in[11];
    const float* bd3 = (const float*)d_in[12];
    const float* cb  = (const float*)d_in[13];

    float* out  = (float*)d_out;
    float* o_idx = out;                       // 131072
    float* o_ze  = o_idx + 131072;            // 8388608
    float* o_zq  = o_ze + 8388608;            // 8388608
    float* o_emb = o_zq + 8388608;            // 8388608
    float* o_X   = o_emb + 8388608;           // 67108864

    float* h1 = (float*)d_ws;                 // B*256
    float* h2 = h1 + (size_t)BB * 256;        // B*128
    float* g1 = h2;                           // reuse (h2 dead after enc3)
    float* g2 = h1;                           // reuse (h1 dead after enc2)

    dim3 blk(256);

    // encoder
    gemm_bias_act<<<dim3(256 / TN ? 256 / TN : 1, BB / TM), blk, 0, stream>>>(
        x, We1, be1, h1, BB, 256, 4096, 0);
    gemm_bias_act<<<dim3(1, BB / TM), blk, 0, stream>>>(
        h1, We2, be2, h2, BB, 128, 256, 0);
    gemm_bias_act<<<dim3(4, BB / TM), blk, 0, stream>>>(
        h2, We3, be3, o_ze, BB, 512, 128, 0);

    // VQ
    vq_argmin<<<dim3(BB * 8 / 64), dim3(512), 0, stream>>>(o_ze, cb, o_idx);
    vq_gather<<<dim3(BB * 512 / 4 / 256), blk, 0, stream>>>(o_ze, o_idx, cb, o_zq, o_emb);

    // decoder
    gemm_bias_act<<<dim3(1, BB / TM), blk, 0, stream>>>(
        o_zq, Wd1, bd1, g1, BB, 128, 512, 0);
    gemm_bias_act<<<dim3(2, BB / TM), blk, 0, stream>>>(
        g1, Wd2, bd2, g2, BB, 256, 128, 0);
    gemm_bias_act<<<dim3(32, BB / TM), blk, 0, stream>>>(
        g2, Wd3, bd3, o_X, BB, 4096, 256, 1);
}

// Round 2
// 1262.042 us; speedup vs baseline: 1.3964x; 1.3964x over previous
//
#include <hip/hip_runtime.h>
#include <cstdint>
#include <cstddef>

// ---------------------------------------------------------------------------
// VQ-VAE forward. B=16384 F=4096 H=512 D=64 M=8 K=512
// Out (floats): [idx 131072][z_e 8388608][z_q 8388608][emb 8388608][X 67108864]
// Encoder + VQ in fp32 (argmin stability). dec3 in bf16 MFMA (sigmoid tail).
// Split-K partials staged in o_X (written last by dec3).
// ws (25.2 MB): h1 | h2 ; decoder phase reuses: g1 | g2b(bf16) | WT(bf16)
// ---------------------------------------------------------------------------

static constexpr int BB = 16384;
static constexpr int TM = 128, TN = 128, TK = 16;

__device__ __forceinline__ unsigned short f2bf(float f) {
    union { float f; uint32_t u; } v; v.f = f;
    uint32_t r = (v.u + 0x7FFFu + ((v.u >> 16) & 1u)) >> 16;
    return (unsigned short)r;
}

// staggered Bs column mapping: breaks the tx*8 4-way bank conflict
__device__ __forceinline__ int bsw(int c) { return c + ((c >> 5) << 2); }

// fp32 tile GEMM. part==null: C = act(A@B + bias). part!=null: raw partial
// for K-slice blockIdx.z into part + z*M*N (combine_act finishes it).
__global__ __launch_bounds__(256) void gemm_fp32(
    const float* __restrict__ A, const float* __restrict__ Bm,
    const float* __restrict__ bias, float* __restrict__ C,
    float* __restrict__ part,
    int M, int N, int Kd, int kLen, int act)
{
    __shared__ float As[TK][TM + 4];
    __shared__ float Bs[TK][140];     // 128 cols staggered: +4 words per 32
    const int tid = threadIdx.x;
    const int bm = blockIdx.y * TM;
    const int bn = blockIdx.x * TN;
    const int kStart = blockIdx.z * kLen;
    const int tx = tid & 15;
    const int ty = tid >> 4;

    const int arow = tid >> 2;
    const int acol = (tid & 3) << 2;
    const int brow = tid >> 5;
    const int bcol = (tid & 31) << 2;

    float acc[8][8];
#pragma unroll
    for (int i = 0; i < 8; i++)
#pragma unroll
        for (int j = 0; j < 8; j++) acc[i][j] = 0.f;

    const float* Ap0 = A + (size_t)(bm + arow) * Kd + acol;
    const float* Ap1 = A + (size_t)(bm + arow + 64) * Kd + acol;
    const float* Bp0 = Bm + (size_t)brow * N + bn + bcol;
    const float* Bp1 = Bm + (size_t)(brow + 8) * N + bn + bcol;

    const int pb0 = bsw(bcol);            // staggered store offsets
    const int prb0 = bsw(tx * 8);         // staggered read offsets
    const int prb1 = prb0 + 4;            // tx*8+4 stays in same 32-group

    for (int k0 = kStart; k0 < kStart + kLen; k0 += TK) {
        const float4 a0 = *(const float4*)(Ap0 + k0);
        const float4 a1 = *(const float4*)(Ap1 + k0);
        const float4 b0 = *(const float4*)(Bp0 + (size_t)k0 * N);
        const float4 b1 = *(const float4*)(Bp1 + (size_t)k0 * N);
        __syncthreads();
        As[acol + 0][arow] = a0.x; As[acol + 1][arow] = a0.y;
        As[acol + 2][arow] = a0.z; As[acol + 3][arow] = a0.w;
        As[acol + 0][arow + 64] = a1.x; As[acol + 1][arow + 64] = a1.y;
        As[acol + 2][arow + 64] = a1.z; As[acol + 3][arow + 64] = a1.w;
        *(float4*)&Bs[brow][pb0]     = b0;
        *(float4*)&Bs[brow + 8][pb0] = b1;
        __syncthreads();
#pragma unroll
        for (int kk = 0; kk < TK; kk++) {
            float a[8], b[8];
            *(float4*)&a[0] = *(const float4*)&As[kk][ty * 8];
            *(float4*)&a[4] = *(const float4*)&As[kk][ty * 8 + 4];
            *(float4*)&b[0] = *(const float4*)&Bs[kk][prb0];
            *(float4*)&b[4] = *(const float4*)&Bs[kk][prb1];
#pragma unroll
            for (int i = 0; i < 8; i++)
#pragma unroll
                for (int j = 0; j < 8; j++)
                    acc[i][j] = fmaf(a[i], b[j], acc[i][j]);
        }
    }

    if (part) {
        float* P = part + (size_t)blockIdx.z * M * N;
#pragma unroll
        for (int i = 0; i < 8; i++) {
            const int row = bm + ty * 8 + i;
            *(float4*)&P[(size_t)row * N + bn + tx * 8]     = *(float4*)&acc[i][0];
            *(float4*)&P[(size_t)row * N + bn + tx * 8 + 4] = *(float4*)&acc[i][4];
        }
        return;
    }

    float bv[8];
#pragma unroll
    for (int j = 0; j < 8; j++) bv[j] = bias[bn + tx * 8 + j];
#pragma unroll
    for (int i = 0; i < 8; i++) {
        const int row = bm + ty * 8 + i;
        float o[8];
#pragma unroll
        for (int j = 0; j < 8; j++) {
            float v = acc[i][j] + bv[j];
            if (act == 0) v = (v > 0.f) ? v : 0.01f * v;
            else          v = 1.0f / (1.0f + __expf(-v));
            o[j] = v;
        }
        *(float4*)&C[(size_t)row * N + bn + tx * 8]     = *(float4*)&o[0];
        *(float4*)&C[(size_t)row * N + bn + tx * 8 + 4] = *(float4*)&o[4];
    }
}

// sum S split-K partials + bias + leaky; write fp32 or bf16
__global__ __launch_bounds__(256) void combine_act(
    const float* __restrict__ part, int S, size_t MN,
    const float* __restrict__ bias, int N,
    float* __restrict__ outF, unsigned short* __restrict__ outB)
{
    const size_t e = ((size_t)blockIdx.x * 256 + threadIdx.x) * 4;
    if (e >= MN) return;
    float4 s = *(const float4*)(part + e);
    for (int i = 1; i < S; i++) {
        const float4 p = *(const float4*)(part + (size_t)i * MN + e);
        s.x += p.x; s.y += p.y; s.z += p.z; s.w += p.w;
    }
    const int col = (int)(e & (size_t)(N - 1));
    const float4 bv = *(const float4*)(bias + col);
    float v0 = s.x + bv.x, v1 = s.y + bv.y, v2 = s.z + bv.z, v3 = s.w + bv.w;
    v0 = (v0 > 0.f) ? v0 : 0.01f * v0;
    v1 = (v1 > 0.f) ? v1 : 0.01f * v1;
    v2 = (v2 > 0.f) ? v2 : 0.01f * v2;
    v3 = (v3 > 0.f) ? v3 : 0.01f * v3;
    if (outF) {
        float4 o; o.x = v0; o.y = v1; o.z = v2; o.w = v3;
        *(float4*)(outF + e) = o;
    } else {
        ushort4 o; o.x = f2bf(v0); o.y = f2bf(v1); o.z = f2bf(v2); o.w = f2bf(v3);
        *(ushort4*)(outB + e) = o;
    }
}

// WT[c][r] = bf16(W[r][c]); W is R x Cc
__global__ __launch_bounds__(256) void transpose_cast(
    const float* __restrict__ W, unsigned short* __restrict__ WT, int R, int Cc)
{
    __shared__ float s[32][33];
    const int tx = threadIdx.x & 31, ty = threadIdx.x >> 5;
    const int c0 = blockIdx.x * 32, r0 = blockIdx.y * 32;
#pragma unroll
    for (int i = 0; i < 4; i++)
        s[ty + i * 8][tx] = W[(size_t)(r0 + ty + i * 8) * Cc + c0 + tx];
    __syncthreads();
#pragma unroll
    for (int i = 0; i < 4; i++)
        WT[(size_t)(c0 + ty + i * 8) * R + r0 + tx] = f2bf(s[tx][ty + i * 8]);
}

// ---------------- dec3: bf16 MFMA, X = sigmoid(Ag @ WT^T + bias) ------------
typedef __attribute__((ext_vector_type(8))) short short8;
typedef __attribute__((ext_vector_type(4))) float f32x4;

#define GLL16(gp, lp) \
    __builtin_amdgcn_global_load_lds( \
        (const __attribute__((address_space(1))) uint32_t*)(gp), \
        (__attribute__((address_space(3))) uint32_t*)(lp), 16, 0, 0)

__global__ __launch_bounds__(256) void gemm_bf16_dec3(
    const unsigned short* __restrict__ Ag,   // 16384 x 256 bf16 row-major
    const unsigned short* __restrict__ Bt,   // 4096 x 256 bf16 row-major (Wd3^T)
    const float* __restrict__ bias, float* __restrict__ C)
{
    // frag-order LDS: t-block (16 rows) x quad x lane -> contiguous 16B slots
    __shared__ short As[4096];   // 8 KB: 8 t-blocks x 512 shorts
    __shared__ short Bs2[4096];
    const int tid = threadIdx.x;
    const int l = tid & 63, w = tid >> 6;
    const int lm = l & 15, lq = l >> 4;
    const int bm = blockIdx.y * 128, bn = blockIdx.x * 128;
    const int wm = (w >> 1) * 64, wn = (w & 1) * 64;

    const int t0 = w * 2, t1 = w * 2 + 1;   // staging t-blocks for this wave
    const unsigned short* ga0 = Ag + (size_t)(bm + t0 * 16 + lm) * 256 + lq * 8;
    const unsigned short* ga1 = Ag + (size_t)(bm + t1 * 16 + lm) * 256 + lq * 8;
    const unsigned short* gb0 = Bt + (size_t)(bn + t0 * 16 + lm) * 256 + lq * 8;
    const unsigned short* gb1 = Bt + (size_t)(bn + t1 * 16 + lm) * 256 + lq * 8;

    f32x4 acc[4][4];
#pragma unroll
    for (int i = 0; i < 4; i++)
#pragma unroll
        for (int j = 0; j < 4; j++) acc[i][j] = (f32x4){0.f, 0.f, 0.f, 0.f};

    for (int k0 = 0; k0 < 256; k0 += 32) {
        __syncthreads();   // previous iteration's reads done
        GLL16(ga0 + k0, &As[t0 * 512]);
        GLL16(ga1 + k0, &As[t1 * 512]);
        GLL16(gb0 + k0, &Bs2[t0 * 512]);
        GLL16(gb1 + k0, &Bs2[t1 * 512]);
        __syncthreads();   // drains vmcnt: staged data visible
        short8 af[4], bf[4];
#pragma unroll
        for (int i = 0; i < 4; i++)
            af[i] = *(const short8*)&As[((w >> 1) * 4 + i) * 512 + lq * 128 + lm * 8];
#pragma unroll
        for (int j = 0; j < 4; j++)
            bf[j] = *(const short8*)&Bs2[((w & 1) * 4 + j) * 512 + lq * 128 + lm * 8];
#pragma unroll
        for (int i = 0; i < 4; i++)
#pragma unroll
            for (int j = 0; j < 4; j++)
                acc[i][j] = __builtin_amdgcn_mfma_f32_16x16x32_bf16(
                    af[i], bf[j], acc[i][j], 0, 0, 0);
    }

#pragma unroll
    for (int i = 0; i < 4; i++) {
#pragma unroll
        for (int j = 0; j < 4; j++) {
            const int col = bn + wn + j * 16 + lm;
            const float bv = bias[col];
#pragma unroll
            for (int r = 0; r < 4; r++) {
                const int row = bm + wm + i * 16 + lq * 4 + r;
                float v = acc[i][j][r] + bv;
                v = 1.0f / (1.0f + __expf(-v));
                C[(size_t)row * 4096 + col] = v;
            }
        }
    }
}

// ---------------- VQ (unchanged fp32) ---------------------------------------
__global__ __launch_bounds__(512) void vq_argmin(
    const float* __restrict__ ze, const float* __restrict__ cb,
    float* __restrict__ idxf)
{
    __shared__ float cbs[64 * 512];
    __shared__ float As[64][68];
    __shared__ float w2s[512];
    const int tid = threadIdx.x;
    const int p0 = blockIdx.x * 64;

    const float4* cb4 = (const float4*)cb;
    float4* cbs4 = (float4*)cbs;
    for (int i = tid; i < 8192; i += 512) cbs4[i] = cb4[i];

    const float4* ze4 = (const float4*)(ze + (size_t)p0 * 64);
    for (int i = tid; i < 1024; i += 512) {
        float4 v = ze4[i];
        int e = i * 4;
        int bo = e >> 9, r = e & 511;
        int d = r >> 3, m = r & 7;
        *(float4*)&As[d][bo * 8 + m] = v;
    }
    __syncthreads();

    {
        float s = 0.f;
#pragma unroll
        for (int d = 0; d < 64; ++d) { float c = cbs[d * 512 + tid]; s = fmaf(c, c, s); }
        w2s[tid] = s;
    }
    __syncthreads();

    const int tx = tid & 63;
    const int ty = tid >> 6;

    float acc[8][8], x2a[8];
#pragma unroll
    for (int i = 0; i < 8; i++) {
        x2a[i] = 0.f;
#pragma unroll
        for (int j = 0; j < 8; j++) acc[i][j] = 0.f;
    }

#pragma unroll 8
    for (int kk = 0; kk < 64; ++kk) {
        float a[8], b[8];
        *(float4*)&a[0] = *(const float4*)&As[kk][ty * 8];
        *(float4*)&a[4] = *(const float4*)&As[kk][ty * 8 + 4];
        *(float4*)&b[0] = *(const float4*)&cbs[kk * 512 + tx * 8];
        *(float4*)&b[4] = *(const float4*)&cbs[kk * 512 + tx * 8 + 4];
#pragma unroll
        for (int i = 0; i < 8; i++) x2a[i] = fmaf(a[i], a[i], x2a[i]);
#pragma unroll
        for (int i = 0; i < 8; i++)
#pragma unroll
            for (int j = 0; j < 8; j++)
                acc[i][j] = fmaf(a[i], b[j], acc[i][j]);
    }

    float w2v[8];
#pragma unroll
    for (int j = 0; j < 8; j++) w2v[j] = w2s[tx * 8 + j];

#pragma unroll
    for (int i = 0; i < 8; i++) {
        float bd = 3.4e38f; int bk = 1 << 30;
#pragma unroll
        for (int j = 0; j < 8; j++) {
            float dsc = (x2a[i] - 2.0f * acc[i][j]) + w2v[j];
            if (dsc < bd) { bd = dsc; bk = tx * 8 + j; }
        }
        for (int off = 32; off > 0; off >>= 1) {
            float od = __shfl_xor(bd, off);
            int   ok = __shfl_xor(bk, off);
            if (od < bd || (od == bd && ok < bk)) { bd = od; bk = ok; }
        }
        if (tx == i) idxf[p0 + ty * 8 + i] = (float)bk;
    }
}

__global__ __launch_bounds__(256) void vq_gather(
    const float* __restrict__ ze, const float* __restrict__ idxf,
    const float* __restrict__ cb,
    float* __restrict__ zq, float* __restrict__ emb)
{
    const int t = blockIdx.x * 256 + threadIdx.x;
    const int e = t * 4;
    const int b = e >> 9, r = e & 511;
    const int d = r >> 3, m = r & 7;
    const float4 z = *(const float4*)(ze + e);
    float q[4];
#pragma unroll
    for (int c = 0; c < 4; c++) {
        int k = (int)idxf[b * 8 + m + c];
        q[c] = cb[d * 512 + k];
    }
    float4 zq4, em4;
    zq4.x = z.x + (q[0] - z.x); zq4.y = z.y + (q[1] - z.y);
    zq4.z = z.z + (q[2] - z.z); zq4.w = z.w + (q[3] - z.w);
    em4.x = q[0]; em4.y = q[1]; em4.z = q[2]; em4.w = q[3];
    *(float4*)(zq + e) = zq4;
    *(float4*)(emb + e) = em4;
}

extern "C" void kernel_launch(void* const* d_in, const int* in_sizes, int n_in,
                              void* d_out, int out_size, void* d_ws, size_t ws_size,
                              hipStream_t stream)
{
    const float* x   = (const float*)d_in[0];
    const float* We1 = (const float*)d_in[1];
    const float* be1 = (const float*)d_in[2];
    const float* We2 = (const float*)d_in[3];
    const float* be2 = (const float*)d_in[4];
    const float* We3 = (const float*)d_in[5];
    const float* be3 = (const float*)d_in[6];
    const float* Wd1 = (const float*)d_in[7];
    const float* bd1 = (const float*)d_in[8];
    const float* Wd2 = (const float*)d_in[9];
    const float* bd2 = (const float*)d_in[10];
    const float* Wd3 = (const float*)d_in[11];
    const float* bd3 = (const float*)d_in[12];
    const float* cb  = (const float*)d_in[13];

    float* out   = (float*)d_out;
    float* o_idx = out;
    float* o_ze  = o_idx + 131072;
    float* o_zq  = o_ze + 8388608;
    float* o_emb = o_zq + 8388608;
    float* o_X   = o_emb + 8388608;   // 268 MB; doubles as split-K scratch

    float* h1 = (float*)d_ws;                          // B*256 f32
    float* h2 = h1 + (size_t)BB * 256;                 // B*128 f32
    // decoder phase reuse (h1/h2 dead):
    float* g1 = h1;                                    // B*128 f32
    unsigned short* g2b = (unsigned short*)(h1 + (size_t)BB * 128); // B*256 bf16
    unsigned short* WT  = (unsigned short*)h2;         // 4096x256 bf16

    // encoder
    gemm_fp32<<<dim3(2, 128, 4), 256, 0, stream>>>(
        x, We1, nullptr, nullptr, o_X, BB, 256, 4096, 1024, 0);
    combine_act<<<4096, 256, 0, stream>>>(o_X, 4, (size_t)BB * 256, be1, 256, h1, nullptr);
    gemm_fp32<<<dim3(1, 128, 2), 256, 0, stream>>>(
        h1, We2, nullptr, nullptr, o_X, BB, 128, 256, 128, 0);
    combine_act<<<2048, 256, 0, stream>>>(o_X, 2, (size_t)BB * 128, be2, 128, h2, nullptr);
    gemm_fp32<<<dim3(4, 128, 1), 256, 0, stream>>>(
        h2, We3, be3, o_ze, nullptr, BB, 512, 128, 128, 0);

    // VQ
    vq_argmin<<<dim3(2048), dim3(512), 0, stream>>>(o_ze, cb, o_idx);
    vq_gather<<<dim3(8192), dim3(256), 0, stream>>>(o_ze, o_idx, cb, o_zq, o_emb);

    // Wd3^T cast (h2 dead after enc3)
    transpose_cast<<<dim3(128, 8), 256, 0, stream>>>(Wd3, WT, 256, 4096);

    // decoder
    gemm_fp32<<<dim3(1, 128, 4), 256, 0, stream>>>(
        o_zq, Wd1, nullptr, nullptr, o_X, BB, 128, 512, 128, 0);
    combine_act<<<2048, 256, 0, stream>>>(o_X, 4, (size_t)BB * 128, bd1, 128, g1, nullptr);
    gemm_fp32<<<dim3(2, 128, 2), 256, 0, stream>>>(
        g1, Wd2, nullptr, nullptr, o_X, BB, 256, 128, 64, 0);
    combine_act<<<4096, 256, 0, stream>>>(o_X, 2, (size_t)BB * 256, bd2, 256, nullptr, g2b);
    gemm_bf16_dec3<<<dim3(32, 128), 256, 0, stream>>>(g2b, WT, bd3, o_X);
}